// Round 15
// baseline (86.641 us; speedup 1.0000x reference)
//
#include <hip/hip_runtime.h>
#include <math.h>

// Problem constants (B=8, P=64, V=32, N_TH1=30 -> D=1626)
#define NBP 512          // B*P
#define VV 32
#define DD 1626
#define DSPAN 407        // dirs per block (4 blocks along dir dim)

// Output layout (flat float32, concatenated in return order)
#define O_POINTS 0                         // (8,64*1626,3)  = 2497536
#define O_DIRH   2497536                   // (8,64,1626,4)  = 3330048
#define O_OVER   5827584                   // (8,64,1)       = 512
#define O_RETR   5828096                   // (8,64,1)       = 512
#define O_MEAN   5828608                   // (8,64,3)       = 1536
#define O_LOCAL  5830144                   // (8,64,32,3)    = 49152

#define L10_2 0.3010299956639812f    // log10(2)
#define L2_10 3.321928094887362f     // log2(10)
#define LH_MIN -66.43856189774725f   // log2(1e-20)

__device__ __forceinline__ float fexp2(float x) {
  return __builtin_amdgcn_exp2f(x);    // raw v_exp_f32
}

// inline direction via hardware v_sin/v_cos
__device__ __forceinline__ void make_dir_fast(int d, float& x, float& y, float& z) {
  if (d < 1624) {
    const int i1 = d / 58 + 1;        // 1..28
    const int i2 = d - (i1 - 1) * 58; // 0..57
    const float STEP = 0.10833078115826873f;        // pi/29
    const float th1 = -1.5707963267948966f + (float)i1 * STEP;
    const float th2 = -3.14159265358979323846f + (float)i2 * STEP;
    const float s1 = __sinf(th1);
    const float c1 = __cosf(th1);
    const float s2 = __sinf(th2);
    const float c2 = __cosf(th2);
    x = c1 * c2; y = c1 * s2; z = s1;
  } else if (d == 1624) {             // pole th1=-pi/2 (numpy f64->f32 values)
    x = -6.123234e-17f; y = -7.49880e-33f; z = -1.0f;
  } else {                            // pole th1=+pi/2
    x = -6.123234e-17f; y = -7.49880e-33f; z = 1.0f;
  }
}

// Pair-cooperative fused SPT: 2 lanes per direction, each lane owns 16
// vertices in registers (48 VGPRs). No LDS, no barriers. Speculative k=1
// (rescale path re-derived only if expo < -20 — exact, ~never taken).
// __launch_bounds__(256,5): cap 102 VGPR >> ~78 live, guarantees 5 waves/SIMD.
__global__ __launch_bounds__(256, 5) void spt_kernel(
    const float* __restrict__ vertices,
    const float* __restrict__ smooth,
    float* __restrict__ out)
{
  const int bp  = blockIdx.x;   // 0..511
  const int bz  = blockIdx.y;   // 0..3
  const int tid = threadIdx.x;
  const int sub = tid & 1;      // which 16-vertex half this lane owns

  const int dbase = bz * DSPAN;
  const int dend  = (DD - dbase) < DSPAN ? (DD - dbase) : DSPAN;  // 407/405

  // ---- load this lane's 16 vertices (48 floats, 12 float4) ----
  float lx[16], ly[16], lz[16];
  {
    const float4* vp4 = (const float4*)(vertices + bp * (VV * 3) + sub * 48);
    float tt[48];
#pragma unroll
    for (int j = 0; j < 12; j++) {
      float4 q = vp4[j];
      tt[4 * j + 0] = q.x; tt[4 * j + 1] = q.y;
      tt[4 * j + 2] = q.z; tt[4 * j + 3] = q.w;
    }
#pragma unroll
    for (int i = 0; i < 16; i++) {
      lx[i] = tt[3 * i + 0];
      ly[i] = tt[3 * i + 1];
      lz[i] = tt[3 * i + 2];
    }
  }

  // ---- mean: local 16-sum + one pair shuffle ----
  float sxa = 0.f, sxb = 0.f, sya = 0.f, syb = 0.f, sza = 0.f, szb = 0.f;
#pragma unroll
  for (int i = 0; i < 16; i += 2) {
    sxa += lx[i]; sxb += lx[i + 1];
    sya += ly[i]; syb += ly[i + 1];
    sza += lz[i]; szb += lz[i + 1];
  }
  float sx = sxa + sxb, sy = sya + syb, sz = sza + szb;
  sx += __shfl_xor(sx, 1);
  sy += __shfl_xor(sy, 1);
  sz += __shfl_xor(sz, 1);
  const float mx = sx * (1.0f / 32.0f);
  const float my = sy * (1.0f / 32.0f);
  const float mz = sz * (1.0f / 32.0f);

#pragma unroll
  for (int i = 0; i < 16; i++) {
    lx[i] -= mx; ly[i] -= my; lz[i] -= mz;
  }

  // ---- side outputs (once, by bz==3 which has the lighter tail) ----
  if (bz == 3) {
    if (tid < 2) {
      float* lp = out + O_LOCAL + bp * (VV * 3) + sub * 48;
#pragma unroll
      for (int i = 0; i < 16; i++) {
        lp[3 * i + 0] = lx[i];
        lp[3 * i + 1] = ly[i];
        lp[3 * i + 2] = lz[i];
      }
    }
    if (tid == 2) {
      out[O_MEAN + bp * 3 + 0] = mx;
      out[O_MEAN + bp * 3 + 1] = my;
      out[O_MEAN + bp * 3 + 2] = mz;
      out[O_OVER + bp] = 0.f;
      out[O_RETR + bp] = 0.f;
    }
  }

  const float p     = smooth[bp];
  const float inv_p = 1.0f / p;
  const float pm1   = p - 1.0f;
  const float plt   = p * L10_2;

#pragma unroll 1
  for (int r = 0; r < 4; ++r) {
    const int idx = r * 128 + (tid >> 1);
    if (idx >= dend) break;               // pair-uniform (both lanes same idx)
    const int d = dbase + idx;
    float dx, dy, dz;
    make_dir_fast(d, dx, dy, dz);

    // ---- speculative fused pass (k=1): u = zv^(p-1); track zmax ----
    float zmax = 0.f;
    float ss0 = 0.f, ss1 = 0.f;
    float ax = 0.f, ay = 0.f, az = 0.f;
#pragma unroll
    for (int i = 0; i < 16; i += 2) {
      float z0 = fmaxf(fmaf(lx[i],     dx, fmaf(ly[i],     dy, lz[i]     * dz)), 0.f);
      float z1 = fmaxf(fmaf(lx[i + 1], dx, fmaf(ly[i + 1], dy, lz[i + 1] * dz)), 0.f);
      zmax = fmaxf(zmax, fmaxf(z0, z1));
      float u0 = fexp2(pm1 * __log2f(z0));   // zv=0 -> -inf -> 0
      float u1 = fexp2(pm1 * __log2f(z1));
      ss0 = fmaf(u0, z0, ss0);
      ss1 = fmaf(u1, z1, ss1);
      ax = fmaf(u0, lx[i], fmaf(u1, lx[i + 1], ax));
      ay = fmaf(u0, ly[i], fmaf(u1, ly[i + 1], ay));
      az = fmaf(u0, lz[i], fmaf(u1, lz[i + 1], az));
    }
    zmax = fmaxf(zmax, __shfl_xor(zmax, 1));

    // rescale check: expo = p*log10(zmax); only if < -20 redo with k
    float kcl = 0.f;
    const float expo = __log2f(zmax) * plt;
    if (expo < -20.f) {                    // rare/never for this data; exact
      float kc = fminf(fmaxf(ceilf((-15.f - expo) * inv_p), 0.f), 20.f);
      kcl = kc * L2_10;
      const float A = p * kcl;             // u = zv^(p-1) * k^p
      ss0 = ss1 = ax = ay = az = 0.f;
#pragma unroll
      for (int i = 0; i < 16; i++) {
        float z0 = fmaxf(fmaf(lx[i], dx, fmaf(ly[i], dy, lz[i] * dz)), 0.f);
        float u0 = fexp2(fmaf(pm1, __log2f(z0), A));
        ss0 = fmaf(u0, z0, ss0);
        ax = fmaf(u0, lx[i], ax);
        ay = fmaf(u0, ly[i], ay);
        az = fmaf(u0, lz[i], az);
      }
    }

    float ss = ss0 + ss1;
    ss += __shfl_xor(ss, 1);
    ax += __shfl_xor(ax, 1);
    ay += __shfl_xor(ay, 1);
    az += __shfl_xor(az, 1);

    float lh = LH_MIN;
    float C2 = 0.f;                        // dhdz_i = u_i * C2
    if (ss > 0.f) {
      lh = inv_p * __log2f(ss);
      C2 = fexp2(-fmaf(pm1, lh, kcl));
    }

    const int pbase = bp * DD + d;
    if (sub == 0) {
      out[O_POINTS + pbase * 3 + 0] = fmaf(C2, ax, mx);
      out[O_POINTS + pbase * 3 + 1] = fmaf(C2, ay, my);
      out[O_POINTS + pbase * 3 + 2] = fmaf(C2, az, mz);
    } else {
      float4 dvh = make_float4(dx, dy, dz, fexp2(lh - kcl));   // w = h/k
      ((float4*)(out + O_DIRH))[pbase] = dvh;
    }
  }
}

extern "C" void kernel_launch(void* const* d_in, const int* in_sizes, int n_in,
                              void* d_out, int out_size, void* d_ws, size_t ws_size,
                              hipStream_t stream) {
  const float* vertices = (const float*)d_in[0];  // (8,64,32,3) f32
  const float* smooth   = (const float*)d_in[1];  // (8,64) f32
  float* out = (float*)d_out;

  spt_kernel<<<dim3(NBP, 4), 256, 0, stream>>>(vertices, smooth, out);
}

// Round 16
// 76.583 us; speedup vs baseline: 1.1313x; 1.1313x over previous
//
#include <hip/hip_runtime.h>
#include <math.h>

// Problem constants (B=8, P=64, V=32, N_TH1=30 -> D=1626)
#define NBP 512          // B*P
#define VV 32
#define DD 1626
#define DHALF 813        // directions per block (2 halves)

// Output layout (flat float32, concatenated in return order)
#define O_POINTS 0                         // (8,64*1626,3)  = 2497536
#define O_DIRH   2497536                   // (8,64,1626,4)  = 3330048
#define O_OVER   5827584                   // (8,64,1)       = 512
#define O_RETR   5828096                   // (8,64,1)       = 512
#define O_MEAN   5828608                   // (8,64,3)       = 1536
#define O_LOCAL  5830144                   // (8,64,32,3)    = 49152

#define L10_2 0.3010299956639812f    // log10(2)
#define L2_10 3.321928094887362f     // log2(10)
#define LH_MIN -66.43856189774725f   // log2(1e-20)

__device__ __forceinline__ float fexp2(float x) {
  return __builtin_amdgcn_exp2f(x);    // raw v_exp_f32
}

// inline direction via hardware v_sin/v_cos
__device__ __forceinline__ void make_dir_fast(int d, float& x, float& y, float& z) {
  if (d < 1624) {
    const int i1 = d / 58 + 1;        // 1..28
    const int i2 = d - (i1 - 1) * 58; // 0..57
    const float STEP = 0.10833078115826873f;        // pi/29
    const float th1 = -1.5707963267948966f + (float)i1 * STEP;
    const float th2 = -3.14159265358979323846f + (float)i2 * STEP;
    const float s1 = __sinf(th1);
    const float c1 = __cosf(th1);
    const float s2 = __sinf(th2);
    const float c2 = __cosf(th2);
    x = c1 * c2; y = c1 * s2; z = s1;
  } else if (d == 1624) {             // pole th1=-pi/2 (numpy f64->f32 values)
    x = -6.123234e-17f; y = -7.49880e-33f; z = -1.0f;
  } else {                            // pole th1=+pi/2
    x = -6.123234e-17f; y = -7.49880e-33f; z = 1.0f;
  }
}

__global__ __launch_bounds__(256) void spt_kernel(
    const float* __restrict__ vertices,
    const float* __restrict__ smooth,
    float* __restrict__ out)
{
  const int bp   = blockIdx.x;   // 0..511
  const int half = blockIdx.y;   // 0..1
  const int tid  = threadIdx.x;

  __shared__ __align__(16) float slvx[VV];
  __shared__ __align__(16) float slvy[VV];
  __shared__ __align__(16) float slvz[VV];

  const int dbase = half * DHALF;

  // ---- wave-redundant mean via shuffle; lv -> LDS; ONE barrier ----
  const int v = tid & 31;
  const float* vp = vertices + bp * (VV * 3) + v * 3;
  const float vx = vp[0], vy = vp[1], vz = vp[2];
  float sx = vx, sy = vy, sz = vz;
#pragma unroll
  for (int m = 16; m >= 1; m >>= 1) {
    sx += __shfl_xor(sx, m);
    sy += __shfl_xor(sy, m);
    sz += __shfl_xor(sz, m);
  }
  const float mx = sx * (1.0f / 32.0f);
  const float my = sy * (1.0f / 32.0f);
  const float mz = sz * (1.0f / 32.0f);
  if (tid < VV) {
    slvx[tid] = vx - mx;
    slvy[tid] = vy - my;
    slvz[tid] = vz - mz;
  }
  __syncthreads();

  // ---- side outputs (once, by half 1) ----
  if (half == 1) {
    if (tid < VV * 3) {
      const int vv = tid / 3, c = tid - vv * 3;
      const float val = (c == 0) ? slvx[vv] : ((c == 1) ? slvy[vv] : slvz[vv]);
      out[O_LOCAL + bp * (VV * 3) + tid] = val;
    }
    if (tid == 96) {
      out[O_MEAN + bp * 3 + 0] = mx;
      out[O_MEAN + bp * 3 + 1] = my;
      out[O_MEAN + bp * 3 + 2] = mz;
      out[O_OVER + bp] = 0.f;
      out[O_RETR + bp] = 0.f;
    }
  }

  const float p     = smooth[bp];
  const float inv_p = 1.0f / p;
  const float pm1   = p - 1.0f;
  const float plt   = p * L10_2;

  const float4* lvx4 = (const float4*)slvx;
  const float4* lvy4 = (const float4*)slvy;
  const float4* lvz4 = (const float4*)slvz;

  auto process = [&](int idx) {
    const int d = dbase + idx;
    float dx, dy, dz;
    make_dir_fast(d, dx, dy, dz);

    // ---- pass 1: zv[i] = relu(lv.dir) ; zmax  (no trans) ----
    float w[VV];                       // holds zv now, w2 later (in place)
    float zmax = 0.f;
#pragma unroll
    for (int j = 0; j < VV / 4; j++) {
      float4 X = lvx4[j], Y = lvy4[j], Z = lvz4[j];
      float z0 = fmaxf(fmaf(X.x, dx, fmaf(Y.x, dy, Z.x * dz)), 0.f);
      float z1 = fmaxf(fmaf(X.y, dx, fmaf(Y.y, dy, Z.y * dz)), 0.f);
      float z2 = fmaxf(fmaf(X.z, dx, fmaf(Y.z, dy, Z.z * dz)), 0.f);
      float z3 = fmaxf(fmaf(X.w, dx, fmaf(Y.w, dy, Z.w * dz)), 0.f);
      w[j * 4 + 0] = z0; w[j * 4 + 1] = z1;
      w[j * 4 + 2] = z2; w[j * 4 + 3] = z3;
      zmax = fmaxf(zmax, fmaxf(fmaxf(z0, z1), fmaxf(z2, z3)));
    }

    // rescale exponent kc (zmax==0 -> log2=-inf -> kc=20)
    const float expo = __log2f(zmax) * plt;
    float kc = 0.f;
    if (expo < -20.f) {
      kc = fminf(fmaxf(ceilf((-15.f - expo) * inv_p), 0.f), 20.f);
    }
    const float kcl = kc * L2_10;      // log2(k)
    const float A   = p * kcl;         // exponent offset for w2

    // ---- pass 2: w2_i = 2^(pm1*log2(zv_i) + p*kcl); zp_i = w2_i*zv_i ----
    float s0 = 0.f, s1 = 0.f, s2 = 0.f, s3 = 0.f;
#pragma unroll
    for (int j = 0; j < VV / 4; j++) {
      float z0 = w[j * 4 + 0], z1 = w[j * 4 + 1];
      float z2 = w[j * 4 + 2], z3 = w[j * 4 + 3];
      float w0 = fexp2(fmaf(pm1, __log2f(z0), A));   // zv=0 -> -inf -> 0
      float w1 = fexp2(fmaf(pm1, __log2f(z1), A));
      float w2 = fexp2(fmaf(pm1, __log2f(z2), A));
      float w3 = fexp2(fmaf(pm1, __log2f(z3), A));
      s0 += w0 * z0;  s1 += w1 * z1;
      s2 += w2 * z2;  s3 += w3 * z3;
      w[j * 4 + 0] = w0; w[j * 4 + 1] = w1;
      w[j * 4 + 2] = w2; w[j * 4 + 3] = w3;
    }
    const float ssum = (s0 + s1) + (s2 + s3);

    float lh = LH_MIN;
    float C2 = 0.f;                    // dhdz_i = w2_i * C2
    if (ssum > 0.f) {
      lh = inv_p * __log2f(ssum);
      C2 = fexp2(-fmaf(pm1, lh, kcl));
    }

    // ---- pass 3: dhdx = C2 * sum w2_i * lv_i  (pure FMAs) ----
    float ax = 0.f, ay = 0.f, az = 0.f;
#pragma unroll
    for (int j = 0; j < VV / 4; j++) {
      float4 X = lvx4[j], Y = lvy4[j], Z = lvz4[j];
      float w0 = w[j * 4 + 0], w1 = w[j * 4 + 1];
      float w2 = w[j * 4 + 2], w3 = w[j * 4 + 3];
      ax = fmaf(w0, X.x, fmaf(w1, X.y, fmaf(w2, X.z, fmaf(w3, X.w, ax))));
      ay = fmaf(w0, Y.x, fmaf(w1, Y.y, fmaf(w2, Y.z, fmaf(w3, Y.w, ay))));
      az = fmaf(w0, Z.x, fmaf(w1, Z.y, fmaf(w2, Z.z, fmaf(w3, Z.w, az))));
    }

    const int pbase = bp * DD + d;
    out[O_POINTS + pbase * 3 + 0] = fmaf(C2, ax, mx);
    out[O_POINTS + pbase * 3 + 1] = fmaf(C2, ay, my);
    out[O_POINTS + pbase * 3 + 2] = fmaf(C2, az, mz);

    // direction_h row as one dwordx4 store (w = h/k)
    float4 dvh = make_float4(dx, dy, dz, fexp2(lh - kcl));
    ((float4*)(out + O_DIRH))[pbase] = dvh;
  };

  process(tid);
  process(256 + tid);
  process(512 + tid);
  if (tid < DHALF - 768) process(768 + tid);   // 45 threads
}

extern "C" void kernel_launch(void* const* d_in, const int* in_sizes, int n_in,
                              void* d_out, int out_size, void* d_ws, size_t ws_size,
                              hipStream_t stream) {
  const float* vertices = (const float*)d_in[0];  // (8,64,32,3) f32
  const float* smooth   = (const float*)d_in[1];  // (8,64) f32
  float* out = (float*)d_out;

  spt_kernel<<<dim3(NBP, 2), 256, 0, stream>>>(vertices, smooth, out);
}